// Round 4
// baseline (195.820 us; speedup 1.0000x reference)
//
#include <hip/hip_runtime.h>
#include <hip/hip_bf16.h>

typedef unsigned short ushort_t;
typedef unsigned int uint_t;
using f32x4  = __attribute__((ext_vector_type(4))) float;
using short8 = __attribute__((ext_vector_type(8))) short;

#define NN 8192

__device__ __forceinline__ ushort_t f2bf(float f) {
  uint_t u = __builtin_bit_cast(uint_t, f);
  u += 0x7FFFu + ((u >> 16) & 1u);   // RNE
  return (ushort_t)(u >> 16);
}

// ---------------------------------------------------------------------------
// K1: Xp = X @ W  -> XpT bf16 [2*64][8192] (row = h*64+c), x0[N][2], x1T[2][N]
// ---------------------------------------------------------------------------
__global__ __launch_bounds__(256, 2) void k1_project(
    const float* __restrict__ X, const float* __restrict__ W,
    const float* __restrict__ attn,
    ushort_t* __restrict__ XpT, float* __restrict__ x0g, float* __restrict__ x1g)
{
  __shared__ float    Xl[32][128];      // 16 KB
  __shared__ ushort_t XpL[128][56];     // 14 KB
  __shared__ float    P0[128][33];
  __shared__ float    P1[128][33];
  const int t  = threadIdx.x;
  const int nb = blockIdx.x * 32;

  #pragma unroll
  for (int r = 0; r < 4; ++r) {
    int chunk = r * 256 + t;
    ((float4*)(&Xl[0][0]))[chunk] = ((const float4*)(X + (size_t)nb * 128))[chunk];
  }
  __syncthreads();

  const int p = t & 127;
  const int g = t >> 7;
  const int h = p & 1, c = p >> 1;

  float acc[16];
  #pragma unroll
  for (int n = 0; n < 16; ++n) acc[n] = 0.f;

  for (int jc = 0; jc < 4; ++jc) {
    float wreg[32];
    #pragma unroll
    for (int jj = 0; jj < 32; ++jj) wreg[jj] = W[(jc * 32 + jj) * 128 + p];
    #pragma unroll
    for (int n = 0; n < 16; ++n) {
      const float4* xr = (const float4*)(&Xl[g * 16 + n][jc * 32]);
      float s = acc[n];
      #pragma unroll
      for (int q = 0; q < 8; ++q) {
        float4 xv = xr[q];
        s += xv.x * wreg[q*4+0] + xv.y * wreg[q*4+1] + xv.z * wreg[q*4+2] + xv.w * wreg[q*4+3];
      }
      acc[n] = s;
    }
  }

  const float a0 = attn[p];
  const float a1 = attn[128 + p];
  const int   row = h * 64 + c;
  #pragma unroll
  for (int n = 0; n < 16; ++n) {
    P0[p][g * 16 + n]  = acc[n] * a0;
    P1[p][g * 16 + n]  = acc[n] * a1;
    XpL[row][g * 16 + n] = f2bf(acc[n]);
  }
  __syncthreads();

  if (t < 128) {
    ushort_t* dst = XpT + (size_t)t * NN + nb;
    const uint4* src = (const uint4*)(&XpL[t][0]);
    ((uint4*)dst)[0] = src[0];
    ((uint4*)dst)[1] = src[1];
    ((uint4*)dst)[2] = src[2];
    ((uint4*)dst)[3] = src[3];
  }
  if (t < 64) {
    int node = t >> 1, hh = t & 1;
    float s0 = 0.f, s1 = 0.f;
    #pragma unroll
    for (int cc = 0; cc < 64; ++cc) {
      s0 += P0[cc * 2 + hh][node];
      s1 += P1[cc * 2 + hh][node];
    }
    x0g[(nb + node) * 2 + hh] = s0;
    x1g[hh * NN + nb + node]  = s1;
  }
}

// ---------------------------------------------------------------------------
// K2: BI=16 rows/block, BK=64. B-frags loaded DIRECTLY from L2-resident XpT
// into regs (no B LDS). Only P goes through LDS (double-buffered, 1 barrier).
// 4 waves: wave w -> head (w&1), col-blocks {(w>>1)*2, +1}.
// ---------------------------------------------------------------------------
__global__ __launch_bounds__(256, 6) void k2_main(
    const float* __restrict__ A, const ushort_t* __restrict__ XpT,
    const float* __restrict__ x0g, const float* __restrict__ x1g,
    float* __restrict__ part, float* __restrict__ denp,
    const int S, const int KS)
{
  __shared__ __align__(16) ushort_t Pl[2 * 32 * 64];   // 8 KB: 2 bufs x [32][64]
  const int t  = threadIdx.x;
  const int b  = blockIdx.x;
  const int rb = b / S, sp = b % S;
  const int ib = rb * 16;
  const int k0 = sp * KS;
  const int lane = t & 63, w = t >> 6;
  const int hw  = w & 1;           // head
  const int cb2 = (w >> 1) << 1;   // col-block base {0,2}
  const int pr  = t >> 4;          // row 0..15
  const int pkE = (t & 15) * 4;    // col element offset 0..60

  const float2 x0v = *(const float2*)(x0g + (ib + pr) * 2);

  // B-frag element offsets into XpT (row*NN + k-lane offset); +kt at use
  int boffE[2][2];
  #pragma unroll
  for (int ks = 0; ks < 2; ++ks)
    #pragma unroll
    for (int c = 0; c < 2; ++c) {
      int row = hw * 64 + (cb2 + c) * 16 + (lane & 15);
      boffE[ks][c] = row * NN + ks * 32 + (lane >> 4) * 8;
    }

  // Pl write byte offsets (XOR swizzle ^((row&7)<<4)), one per head
  int plwB[2];
  #pragma unroll
  for (int hh = 0; hh < 2; ++hh) {
    int row = hh * 16 + pr;
    plwB[hh] = (row * 128 + pkE * 2) ^ ((row & 7) << 4);
  }
  // A-frag read byte offsets
  int aoffB[2];
  {
    int row = hw * 16 + (lane & 15);
    #pragma unroll
    for (int ks = 0; ks < 2; ++ks)
      aoffB[ks] = (row * 128 + ks * 64 + (lane >> 4) * 16) ^ ((row & 7) << 4);
  }

  f32x4 acc[2] = {};
  float den0 = 0.f, den1 = 0.f;

  const float* Ap  = A   + (size_t)(ib + pr) * NN + k0 + pkE;
  const float* Xq0 = x1g + k0 + pkE;
  const float* Xq1 = x1g + NN + k0 + pkE;
  const int nt = KS >> 6;

  float4 aC = *(const float4*)(Ap);

  for (int tt = 0; tt < nt; ++tt) {
    const int kt  = k0 + (tt << 6);
    const int par = tt & 1;
    const bool pf = (tt + 1 < nt);

    float4 aN;
    if (pf) aN = *(const float4*)(Ap + ((tt + 1) << 6));     // HBM prefetch
    float4 xv0 = *(const float4*)(Xq0 + (tt << 6));          // L2/L1 JIT
    float4 xv1 = *(const float4*)(Xq1 + (tt << 6));

    short8 bf[2][2];                                          // L2 JIT
    #pragma unroll
    for (int ks = 0; ks < 2; ++ks)
      #pragma unroll
      for (int c = 0; c < 2; ++c)
        bf[ks][c] = *(const short8*)(XpT + (size_t)(boffE[ks][c] + kt));

    // ---- P compute: this thread's row, 4 cols, 2 heads ----
    float av[4]  = {aC.x, aC.y, aC.z, aC.w};
    float x1a[4] = {xv0.x, xv0.y, xv0.z, xv0.w};
    float x1b[4] = {xv1.x, xv1.y, xv1.z, xv1.w};
    ushort_t b0[4], b1[4];
    #pragma unroll
    for (int j = 0; j < 4; ++j) {
      float s0 = x0v.x + x1a[j];
      float p0 = av[j] * __expf(fmaxf(s0, 0.2f * s0));
      den0 += p0;  b0[j] = f2bf(p0);
      float s1 = x0v.y + x1b[j];
      float p1 = av[j] * __expf(fmaxf(s1, 0.2f * s1));
      den1 += p1;  b1[j] = f2bf(p1);
    }

    char* plb = (char*)Pl + par * 4096;
    uint2 v0; v0.x = (uint_t)b0[0] | ((uint_t)b0[1] << 16);
              v0.y = (uint_t)b0[2] | ((uint_t)b0[3] << 16);
    uint2 v1; v1.x = (uint_t)b1[0] | ((uint_t)b1[1] << 16);
              v1.y = (uint_t)b1[2] | ((uint_t)b1[3] << 16);
    *(uint2*)(plb + plwB[0]) = v0;
    *(uint2*)(plb + plwB[1]) = v1;

    // single barrier: writes(t) visible before reads(t); program order makes
    // reads(t) precede writes(t+2) to the same buffer.
    asm volatile("s_waitcnt lgkmcnt(0)" ::: "memory");
    __builtin_amdgcn_s_barrier();
    asm volatile("" ::: "memory");

    #pragma unroll
    for (int ks = 0; ks < 2; ++ks) {
      short8 af = *(const short8*)(plb + aoffB[ks]);
      acc[0] = __builtin_amdgcn_mfma_f32_16x16x32_bf16(af, bf[ks][0], acc[0], 0, 0, 0);
      acc[1] = __builtin_amdgcn_mfma_f32_16x16x32_bf16(af, bf[ks][1], acc[1], 0, 0, 0);
    }

    if (pf) aC = aN;
  }

  // den: butterfly within 16-lane row group
  #pragma unroll
  for (int d = 1; d < 16; d <<= 1) {
    den0 += __shfl_xor(den0, d, 16);
    den1 += __shfl_xor(den1, d, 16);
  }
  if ((t & 15) == 0) {
    float2 dv; dv.x = den0; dv.y = den1;
    *(float2*)(denp + ((size_t)sp * NN + ib + pr) * 2) = dv;
  }

  // partial numerators (C/D layout: col=lane&15, row=(lane>>4)*4+r)
  float* pbase = part + ((size_t)sp * NN + ib) * 128;
  #pragma unroll
  for (int c = 0; c < 2; ++c)
    #pragma unroll
    for (int r = 0; r < 4; ++r) {
      int lr  = (lane >> 4) * 4 + r;
      int col = (cb2 + c) * 16 + (lane & 15);
      pbase[lr * 128 + hw * 64 + col] = acc[c][r];
    }
}

// ---------------------------------------------------------------------------
// K3: combine splits, normalize, add bias.
// ---------------------------------------------------------------------------
__global__ __launch_bounds__(256) void k3_finish(
    const float* __restrict__ part, const float* __restrict__ denp,
    const float* __restrict__ bias, float* __restrict__ out, const int S)
{
  const int idx = blockIdx.x * 256 + threadIdx.x;
  const int i  = idx >> 5;
  const int hc = (idx & 31) * 4;
  const int h  = hc >> 6;
  float4 s; s.x = s.y = s.z = s.w = 0.f;
  float d = 0.f;
  for (int sp = 0; sp < S; ++sp) {
    float4 v = *(const float4*)(part + ((size_t)sp * NN + i) * 128 + hc);
    s.x += v.x; s.y += v.y; s.z += v.z; s.w += v.w;
    d += denp[((size_t)sp * NN + i) * 2 + h];
  }
  const float sc = 1.f / (d + 0.001f);
  float4 bv = *(const float4*)(bias + hc);
  float4 o;
  o.x = s.x * sc + bv.x;
  o.y = s.y * sc + bv.y;
  o.z = s.z * sc + bv.z;
  o.w = s.w * sc + bv.w;
  *(float4*)(out + (size_t)i * 128 + hc) = o;
}

extern "C" void kernel_launch(void* const* d_in, const int* in_sizes, int n_in,
                              void* d_out, int out_size, void* d_ws, size_t ws_size,
                              hipStream_t stream) {
  const float* A    = (const float*)d_in[0];
  const float* X    = (const float*)d_in[1];
  const float* W    = (const float*)d_in[2];
  const float* attn = (const float*)d_in[3];
  const float* bias = (const float*)d_in[4];
  float* out = (float*)d_out;

  char* ws = (char*)d_ws;
  size_t off = 0;
  ushort_t* XpT = (ushort_t*)(ws + off); off += (size_t)128 * NN * sizeof(ushort_t);
  float* x0g = (float*)(ws + off); off += (size_t)NN * 2 * sizeof(float);
  float* x1g = (float*)(ws + off); off += (size_t)2 * NN * sizeof(float);

  int S = 4;
  while (S > 1) {
    size_t need = off + (size_t)S * NN * 2 * 4 + (size_t)S * NN * 128 * 4;
    if (need <= ws_size) break;
    S >>= 1;
  }
  float* denp = (float*)(ws + off); off += (size_t)S * NN * 2 * sizeof(float);
  float* part = (float*)(ws + off);
  const int KS = NN / S;

  k1_project<<<256, 256, 0, stream>>>(X, W, attn, XpT, x0g, x1g);
  k2_main<<<(NN / 16) * S, 256, 0, stream>>>(A, XpT, x0g, x1g, part, denp, S, KS);
  k3_finish<<<1024, 256, 0, stream>>>(part, denp, bias, out, S);
}